// Round 2
// baseline (661.703 us; speedup 1.0000x reference)
//
#include <hip/hip_runtime.h>

#define N_NODES 75000
#define N_EDGES 1200000
#define DIM 64

// ---------------------------------------------------------------------------
// Kernel A (f64): fold e1 through w_k and e2 through w_q:
//   a[d] = sum_j e1[j] * w_k[j][d]     (so h_src[i] = p_u[i] . a)
//   b[d] = sum_j e2[j] * w_q[j][d]     (so h_dst[i] = d_u[i] . b)
// ---------------------------------------------------------------------------
__global__ void vec_precompute(const float* __restrict__ w_q,
                               const float* __restrict__ w_k,
                               const float* __restrict__ e1,
                               const float* __restrict__ e2,
                               double* __restrict__ a,
                               double* __restrict__ b) {
    int t = threadIdx.x;
    if (t < DIM) {
        double s = 0.0;
        #pragma unroll
        for (int j = 0; j < DIM; ++j) s += (double)e1[j] * (double)w_k[j * DIM + t];
        a[t] = s;
    } else if (t < 2 * DIM) {
        int d = t - DIM;
        double s = 0.0;
        #pragma unroll
        for (int j = 0; j < DIM; ++j) s += (double)e2[j] * (double)w_q[j * DIM + d];
        b[d] = s;
    }
}

// ---------------------------------------------------------------------------
// Kernel B: per-node precompute. One thread per node.
//   h_src[i] = p_u[i] . a     (f64)
//   h_dst[i] = d_u[i] . b     (f64)
//   wv[i][j] = sum_d w_v[j][d] * p_u[i][d]   (f32 — no cancellation path)
// ---------------------------------------------------------------------------
__global__ __launch_bounds__(256) void node_kernel(
    const float* __restrict__ d_u, const float* __restrict__ p_u,
    const float* __restrict__ w_v,
    const double* __restrict__ a_vec, const double* __restrict__ b_vec,
    double* __restrict__ h_src, double* __restrict__ h_dst,
    float* __restrict__ wv_out) {
    int i = blockIdx.x * 256 + threadIdx.x;
    if (i >= N_NODES) return;

    // Load p_u row into registers (16 x float4 = 64 floats).
    float p[DIM];
    const float4* prow = (const float4*)(p_u + (size_t)i * DIM);
    #pragma unroll
    for (int k = 0; k < DIM / 4; ++k) {
        float4 v = prow[k];
        p[4 * k + 0] = v.x; p[4 * k + 1] = v.y;
        p[4 * k + 2] = v.z; p[4 * k + 3] = v.w;
    }

    // h_src (f64)
    double hs = 0.0;
    #pragma unroll
    for (int d = 0; d < DIM; ++d) hs += (double)p[d] * a_vec[d];
    h_src[i] = hs;

    // h_dst (f64, stream d_u row)
    double hd = 0.0;
    const float4* drow = (const float4*)(d_u + (size_t)i * DIM);
    #pragma unroll
    for (int k = 0; k < DIM / 4; ++k) {
        float4 v = drow[k];
        hd += (double)v.x * b_vec[4 * k + 0] + (double)v.y * b_vec[4 * k + 1] +
              (double)v.z * b_vec[4 * k + 2] + (double)v.w * b_vec[4 * k + 3];
    }
    h_dst[i] = hd;

    // wv row (f32): 64 dots of (w_v row, p). w_v accesses are wave-uniform.
    float* wvrow = wv_out + (size_t)i * DIM;
    for (int j = 0; j < DIM; j += 4) {
        float a0 = 0.f, a1 = 0.f, a2 = 0.f, a3 = 0.f;
        #pragma unroll
        for (int d = 0; d < DIM; ++d) {
            float pd = p[d];
            a0 += w_v[(j + 0) * DIM + d] * pd;
            a1 += w_v[(j + 1) * DIM + d] * pd;
            a2 += w_v[(j + 2) * DIM + d] * pd;
            a3 += w_v[(j + 3) * DIM + d] * pd;
        }
        float4 r; r.x = a0; r.y = a1; r.z = a2; r.w = a3;
        ((float4*)wvrow)[j >> 2] = r;
    }
}

// ---------------------------------------------------------------------------
// Kernel C: denom[dst] += h_src[src] + h_dst[dst]  (f64 atomics — order-proof)
// ---------------------------------------------------------------------------
__global__ __launch_bounds__(256) void edge_denom(
    const int* __restrict__ src, const int* __restrict__ dst,
    const double* __restrict__ h_src, const double* __restrict__ h_dst,
    double* __restrict__ denom) {
    int e = blockIdx.x * 256 + threadIdx.x;
    if (e >= N_EDGES) return;
    int s = src[e];
    int d = dst[e];
    atomicAdd(&denom[d], h_src[s] + h_dst[d]);
}

// ---------------------------------------------------------------------------
// Kernel D: scatter messages. One wave (64 lanes) per edge, lane = dim.
//   coef = (h_src[s] + h_dst[d]) / denom[d]            (f64)
//   acc[d][lane] += wv[s][lane] * coef                  (f64 atomics)
// ---------------------------------------------------------------------------
__global__ __launch_bounds__(256) void edge_scatter(
    const int* __restrict__ src, const int* __restrict__ dst,
    const double* __restrict__ h_src, const double* __restrict__ h_dst,
    const double* __restrict__ denom, const float* __restrict__ wv,
    double* __restrict__ acc) {
    int gtid = blockIdx.x * 256 + threadIdx.x;
    int e = gtid >> 6;          // global wave id = edge id
    int lane = threadIdx.x & 63;
    if (e >= N_EDGES) return;
    int s = src[e];
    int d = dst[e];
    double coef = (h_src[s] + h_dst[d]) / denom[d];
    double m = (double)wv[(size_t)s * DIM + lane] * coef;
    atomicAdd(&acc[(size_t)d * DIM + lane], m);
}

// ---------------------------------------------------------------------------
// Kernel E: cast f64 accumulator -> f32 output.
// ---------------------------------------------------------------------------
__global__ __launch_bounds__(256) void finalize(
    const double* __restrict__ acc, float* __restrict__ out) {
    int i = blockIdx.x * 256 + threadIdx.x;
    if (i < N_NODES * DIM) out[i] = (float)acc[i];
}

// ---------------------------------------------------------------------------
// Launch
// ---------------------------------------------------------------------------
extern "C" void kernel_launch(void* const* d_in, const int* in_sizes, int n_in,
                              void* d_out, int out_size, void* d_ws, size_t ws_size,
                              hipStream_t stream) {
    const float* d_u = (const float*)d_in[0];
    const float* p_u = (const float*)d_in[1];
    const float* w_q = (const float*)d_in[2];
    const float* w_k = (const float*)d_in[3];
    const float* w_v = (const float*)d_in[4];
    const float* e1  = (const float*)d_in[5];
    const float* e2  = (const float*)d_in[6];
    const int*   src = (const int*)d_in[7];
    const int*   dst = (const int*)d_in[8];
    float* out = (float*)d_out;

    // Workspace layout (8B-aligned doubles first, then f32 wv):
    //   a[64] | b[64] | h_src[N] | h_dst[N] | denom[N] | acc[N*64] | wv[N*64]f32
    double* a     = (double*)d_ws;
    double* b     = a + DIM;
    double* h_src = b + DIM;
    double* h_dst = h_src + N_NODES;
    double* denom = h_dst + N_NODES;
    double* acc   = denom + N_NODES;
    float*  wv    = (float*)(acc + (size_t)N_NODES * DIM);

    // Zero accumulators (harness poisons d_ws with 0xAA each call).
    hipMemsetAsync(acc, 0, sizeof(double) * (size_t)N_NODES * DIM, stream);
    hipMemsetAsync(denom, 0, sizeof(double) * (size_t)N_NODES, stream);

    vec_precompute<<<1, 128, 0, stream>>>(w_q, w_k, e1, e2, a, b);

    node_kernel<<<(N_NODES + 255) / 256, 256, 0, stream>>>(
        d_u, p_u, w_v, a, b, h_src, h_dst, wv);

    edge_denom<<<(N_EDGES + 255) / 256, 256, 0, stream>>>(
        src, dst, h_src, h_dst, denom);

    // one wave per edge -> N_EDGES*64 threads
    edge_scatter<<<((size_t)N_EDGES * 64 + 255) / 256, 256, 0, stream>>>(
        src, dst, h_src, h_dst, denom, wv, acc);

    finalize<<<(N_NODES * DIM + 255) / 256, 256, 0, stream>>>(acc, out);
}

// Round 3
// 364.171 us; speedup vs baseline: 1.8170x; 1.8170x over previous
//
#include <hip/hip_runtime.h>

#define N_NODES 75000
#define N_EDGES 1200000
#define DIM 64
#define SCAN_BLK 1024
#define N_SCAN_BLKS ((N_NODES + SCAN_BLK - 1) / SCAN_BLK)   // 74

// ---------------------------------------------------------------------------
// Kernel A (f64): fold e1 through w_k and e2 through w_q:
//   a[d] = sum_j e1[j] * w_k[j][d]   (h_src[i] = p_u[i] . a)
//   b[d] = sum_j e2[j] * w_q[j][d]   (h_dst[i] = d_u[i] . b)
// ---------------------------------------------------------------------------
__global__ void vec_precompute(const float* __restrict__ w_q,
                               const float* __restrict__ w_k,
                               const float* __restrict__ e1,
                               const float* __restrict__ e2,
                               double* __restrict__ a,
                               double* __restrict__ b) {
    int t = threadIdx.x;
    if (t < DIM) {
        double s = 0.0;
        #pragma unroll
        for (int j = 0; j < DIM; ++j) s += (double)e1[j] * (double)w_k[j * DIM + t];
        a[t] = s;
    } else if (t < 2 * DIM) {
        int d = t - DIM;
        double s = 0.0;
        #pragma unroll
        for (int j = 0; j < DIM; ++j) s += (double)e2[j] * (double)w_q[j * DIM + d];
        b[d] = s;
    }
}

// ---------------------------------------------------------------------------
// Kernel B: per-node precompute (unchanged from R2 — keeps f64 h values
// bit-identical). h_src/h_dst in f64; wv = p_u @ w_v^T in f32.
// ---------------------------------------------------------------------------
__global__ __launch_bounds__(256) void node_kernel(
    const float* __restrict__ d_u, const float* __restrict__ p_u,
    const float* __restrict__ w_v,
    const double* __restrict__ a_vec, const double* __restrict__ b_vec,
    double* __restrict__ h_src, double* __restrict__ h_dst,
    float* __restrict__ wv_out) {
    int i = blockIdx.x * 256 + threadIdx.x;
    if (i >= N_NODES) return;

    float p[DIM];
    const float4* prow = (const float4*)(p_u + (size_t)i * DIM);
    #pragma unroll
    for (int k = 0; k < DIM / 4; ++k) {
        float4 v = prow[k];
        p[4 * k + 0] = v.x; p[4 * k + 1] = v.y;
        p[4 * k + 2] = v.z; p[4 * k + 3] = v.w;
    }

    double hs = 0.0;
    #pragma unroll
    for (int d = 0; d < DIM; ++d) hs += (double)p[d] * a_vec[d];
    h_src[i] = hs;

    double hd = 0.0;
    const float4* drow = (const float4*)(d_u + (size_t)i * DIM);
    #pragma unroll
    for (int k = 0; k < DIM / 4; ++k) {
        float4 v = drow[k];
        hd += (double)v.x * b_vec[4 * k + 0] + (double)v.y * b_vec[4 * k + 1] +
              (double)v.z * b_vec[4 * k + 2] + (double)v.w * b_vec[4 * k + 3];
    }
    h_dst[i] = hd;

    float* wvrow = wv_out + (size_t)i * DIM;
    for (int j = 0; j < DIM; j += 4) {
        float a0 = 0.f, a1 = 0.f, a2 = 0.f, a3 = 0.f;
        #pragma unroll
        for (int d = 0; d < DIM; ++d) {
            float pd = p[d];
            a0 += w_v[(j + 0) * DIM + d] * pd;
            a1 += w_v[(j + 1) * DIM + d] * pd;
            a2 += w_v[(j + 2) * DIM + d] * pd;
            a3 += w_v[(j + 3) * DIM + d] * pd;
        }
        float4 r; r.x = a0; r.y = a1; r.z = a2; r.w = a3;
        ((float4*)wvrow)[j >> 2] = r;
    }
}

// ---------------------------------------------------------------------------
// CSR build step 1: histogram of dst.
// ---------------------------------------------------------------------------
__global__ __launch_bounds__(256) void hist_kernel(
    const int* __restrict__ dst, int* __restrict__ cnt) {
    int e = blockIdx.x * 256 + threadIdx.x;
    if (e >= N_EDGES) return;
    atomicAdd(&cnt[dst[e]], 1);
}

// CSR build step 2a: per-block exclusive scan (Hillis-Steele in LDS).
__global__ __launch_bounds__(SCAN_BLK) void scan1_kernel(
    const int* __restrict__ cnt, int* __restrict__ row,
    int* __restrict__ bsum) {
    __shared__ int sh[SCAN_BLK];
    int tid = threadIdx.x;
    int i = blockIdx.x * SCAN_BLK + tid;
    int v = (i < N_NODES) ? cnt[i] : 0;
    sh[tid] = v;
    __syncthreads();
    for (int off = 1; off < SCAN_BLK; off <<= 1) {
        int t = (tid >= off) ? sh[tid - off] : 0;
        __syncthreads();
        sh[tid] += t;
        __syncthreads();
    }
    if (i < N_NODES) row[i] = sh[tid] - v;   // exclusive
    if (tid == SCAN_BLK - 1) bsum[blockIdx.x] = sh[tid];
}

// CSR build step 2b: exclusive scan of the 74 block sums (one block).
__global__ __launch_bounds__(128) void scan2_kernel(int* __restrict__ bsum) {
    __shared__ int sh[128];
    int tid = threadIdx.x;
    int v = (tid < N_SCAN_BLKS) ? bsum[tid] : 0;
    sh[tid] = v;
    __syncthreads();
    for (int off = 1; off < 128; off <<= 1) {
        int t = (tid >= off) ? sh[tid - off] : 0;
        __syncthreads();
        sh[tid] += t;
        __syncthreads();
    }
    if (tid < N_SCAN_BLKS) bsum[tid] = sh[tid] - v;   // exclusive
}

// CSR build step 2c: add block offsets; init cursor = row_start.
__global__ __launch_bounds__(256) void scan3_kernel(
    int* __restrict__ row, const int* __restrict__ bsum,
    int* __restrict__ cursor) {
    int i = blockIdx.x * 256 + threadIdx.x;
    if (i >= N_NODES) return;
    int r = row[i] + bsum[i / SCAN_BLK];
    row[i] = r;
    cursor[i] = r;
}

// CSR build step 3: scatter edges into rows; precompute f64 edge score c.
__global__ __launch_bounds__(256) void build_kernel(
    const int* __restrict__ src, const int* __restrict__ dst,
    const double* __restrict__ h_src, const double* __restrict__ h_dst,
    int* __restrict__ cursor,
    int* __restrict__ csr_src, double* __restrict__ csr_c) {
    int e = blockIdx.x * 256 + threadIdx.x;
    if (e >= N_EDGES) return;
    int s = src[e];
    int d = dst[e];
    double c = h_src[s] + h_dst[d];
    int pos = atomicAdd(&cursor[d], 1);
    csr_src[pos] = s;
    csr_c[pos] = c;
}

// ---------------------------------------------------------------------------
// Gather: one wave per dst node, lane = dim.
//   denom = sum of row's c (f64 butterfly reduce)
//   out[node][lane] = (f32) sum_j wv[s_j][lane] * (c_j/denom)
// Row's (s, c) loaded coalesced lane-parallel, then __shfl-broadcast per j.
// ---------------------------------------------------------------------------
__global__ __launch_bounds__(256) void node_gather(
    const int* __restrict__ row, const int* __restrict__ cnt,
    const int* __restrict__ csr_src, const double* __restrict__ csr_c,
    const double* __restrict__ h_src, const double* __restrict__ h_dst,
    const float* __restrict__ wv, float* __restrict__ out) {
    int gtid = blockIdx.x * 256 + threadIdx.x;
    int node = gtid >> 6;
    int lane = threadIdx.x & 63;
    if (node >= N_NODES) return;

    int start = row[node];
    int deg = cnt[node];

    // First chunk (deg <= 64 in practice): lane-parallel coalesced loads.
    int m0 = deg < 64 ? deg : 64;
    double c0 = 0.0;
    int s0 = 0;
    if (lane < m0) {
        s0 = csr_src[start + lane];
        c0 = csr_c[start + lane];
    }

    // denom = full-row sum (butterfly over first chunk + loop for overflow).
    double r = c0;
    #pragma unroll
    for (int off = 32; off > 0; off >>= 1) r += __shfl_xor(r, off, 64);
    double denom = r;
    for (int base = 64; base < deg; base += 64) {
        int m = deg - base; if (m > 64) m = 64;
        double c = (lane < m) ? csr_c[start + base + lane] : 0.0;
        #pragma unroll
        for (int off = 32; off > 0; off >>= 1) c += __shfl_xor(c, off, 64);
        denom += c;
    }
    double inv = 1.0 / denom;

    // Accumulate: per edge j, broadcast (s, c) via shuffle; coalesced wv row.
    double acc = 0.0;
    for (int j = 0; j < m0; ++j) {
        int s = __shfl(s0, j, 64);
        double coef = __shfl(c0, j, 64) * inv;
        acc += (double)wv[(size_t)s * DIM + lane] * coef;
    }
    for (int base = 64; base < deg; base += 64) {   // rare (deg > 64)
        int m = deg - base; if (m > 64) m = 64;
        int s1 = 0; double c1 = 0.0;
        if (lane < m) {
            s1 = csr_src[start + base + lane];
            c1 = csr_c[start + base + lane];
        }
        for (int j = 0; j < m; ++j) {
            int s = __shfl(s1, j, 64);
            double coef = __shfl(c1, j, 64) * inv;
            acc += (double)wv[(size_t)s * DIM + lane] * coef;
        }
    }
    out[(size_t)node * DIM + lane] = (float)acc;
}

// ---------------------------------------------------------------------------
// Launch
// ---------------------------------------------------------------------------
extern "C" void kernel_launch(void* const* d_in, const int* in_sizes, int n_in,
                              void* d_out, int out_size, void* d_ws, size_t ws_size,
                              hipStream_t stream) {
    const float* d_u = (const float*)d_in[0];
    const float* p_u = (const float*)d_in[1];
    const float* w_q = (const float*)d_in[2];
    const float* w_k = (const float*)d_in[3];
    const float* w_v = (const float*)d_in[4];
    const float* e1  = (const float*)d_in[5];
    const float* e2  = (const float*)d_in[6];
    const int*   src = (const int*)d_in[7];
    const int*   dst = (const int*)d_in[8];
    float* out = (float*)d_out;

    // Workspace layout: doubles first (8B aligned), then floats, then ints.
    double* a      = (double*)d_ws;
    double* b      = a + DIM;
    double* h_src  = b + DIM;
    double* h_dst  = h_src + N_NODES;
    double* csr_c  = h_dst + N_NODES;                 // N_EDGES doubles
    float*  wv     = (float*)(csr_c + N_EDGES);       // N_NODES*DIM floats
    int*    cnt    = (int*)(wv + (size_t)N_NODES * DIM);
    int*    row    = cnt + N_NODES;
    int*    cursor = row + N_NODES;
    int*    bsum   = cursor + N_NODES;                // 128 ints
    int*    csr_src= bsum + 128;                      // N_EDGES ints

    hipMemsetAsync(cnt, 0, sizeof(int) * N_NODES, stream);

    vec_precompute<<<1, 128, 0, stream>>>(w_q, w_k, e1, e2, a, b);

    node_kernel<<<(N_NODES + 255) / 256, 256, 0, stream>>>(
        d_u, p_u, w_v, a, b, h_src, h_dst, wv);

    hist_kernel<<<(N_EDGES + 255) / 256, 256, 0, stream>>>(dst, cnt);

    scan1_kernel<<<N_SCAN_BLKS, SCAN_BLK, 0, stream>>>(cnt, row, bsum);
    scan2_kernel<<<1, 128, 0, stream>>>(bsum);
    scan3_kernel<<<(N_NODES + 255) / 256, 256, 0, stream>>>(row, bsum, cursor);

    build_kernel<<<(N_EDGES + 255) / 256, 256, 0, stream>>>(
        src, dst, h_src, h_dst, cursor, csr_src, csr_c);

    // one wave per node -> N_NODES*64 threads (exactly 18750 blocks of 256)
    node_gather<<<(N_NODES * 64 + 255) / 256, 256, 0, stream>>>(
        row, cnt, csr_src, csr_c, h_src, h_dst, wv, out);
}

// Round 4
// 348.875 us; speedup vs baseline: 1.8967x; 1.0438x over previous
//
#include <hip/hip_runtime.h>

#define N_NODES 75000
#define N_EDGES 1200000
#define DIM 64
#define SCAN_BLK 1024
#define N_SCAN_BLKS ((N_NODES + SCAN_BLK - 1) / SCAN_BLK)   // 74

// ---------------------------------------------------------------------------
// Kernel A (f64): a[d] = sum_j e1[j]*w_k[j][d];  b[d] = sum_j e2[j]*w_q[j][d]
// ---------------------------------------------------------------------------
__global__ void vec_precompute(const float* __restrict__ w_q,
                               const float* __restrict__ w_k,
                               const float* __restrict__ e1,
                               const float* __restrict__ e2,
                               double* __restrict__ a,
                               double* __restrict__ b) {
    int t = threadIdx.x;
    if (t < DIM) {
        double s = 0.0;
        #pragma unroll
        for (int j = 0; j < DIM; ++j) s += (double)e1[j] * (double)w_k[j * DIM + t];
        a[t] = s;
    } else if (t < 2 * DIM) {
        int d = t - DIM;
        double s = 0.0;
        #pragma unroll
        for (int j = 0; j < DIM; ++j) s += (double)e2[j] * (double)w_q[j * DIM + d];
        b[d] = s;
    }
}

// ---------------------------------------------------------------------------
// Kernel B: per-node precompute. h_src/h_dst f64 (precision-critical);
// wv = p_u @ w_v^T in f32. FULLY unrolled so every w_v index is a
// compile-time constant -> scalar s_load broadcasts, not vector loads.
// ---------------------------------------------------------------------------
__global__ __launch_bounds__(256) void node_kernel(
    const float* __restrict__ d_u, const float* __restrict__ p_u,
    const float* __restrict__ w_v,
    const double* __restrict__ a_vec, const double* __restrict__ b_vec,
    double* __restrict__ h_src, double* __restrict__ h_dst,
    float* __restrict__ wv_out) {
    int i = blockIdx.x * 256 + threadIdx.x;
    if (i >= N_NODES) return;

    float p[DIM];
    const float4* prow = (const float4*)(p_u + (size_t)i * DIM);
    #pragma unroll
    for (int k = 0; k < DIM / 4; ++k) {
        float4 v = prow[k];
        p[4 * k + 0] = v.x; p[4 * k + 1] = v.y;
        p[4 * k + 2] = v.z; p[4 * k + 3] = v.w;
    }

    double hs = 0.0;
    #pragma unroll
    for (int d = 0; d < DIM; ++d) hs += (double)p[d] * a_vec[d];
    h_src[i] = hs;

    double hd = 0.0;
    const float4* drow = (const float4*)(d_u + (size_t)i * DIM);
    #pragma unroll
    for (int k = 0; k < DIM / 4; ++k) {
        float4 v = drow[k];
        hd += (double)v.x * b_vec[4 * k + 0] + (double)v.y * b_vec[4 * k + 1] +
              (double)v.z * b_vec[4 * k + 2] + (double)v.w * b_vec[4 * k + 3];
    }
    h_dst[i] = hd;

    float* wvrow = wv_out + (size_t)i * DIM;
    #pragma unroll
    for (int j = 0; j < DIM; j += 4) {
        float a0 = 0.f, a1 = 0.f, a2 = 0.f, a3 = 0.f;
        #pragma unroll
        for (int d = 0; d < DIM; ++d) {
            float pd = p[d];
            a0 += w_v[(j + 0) * DIM + d] * pd;
            a1 += w_v[(j + 1) * DIM + d] * pd;
            a2 += w_v[(j + 2) * DIM + d] * pd;
            a3 += w_v[(j + 3) * DIM + d] * pd;
        }
        float4 r; r.x = a0; r.y = a1; r.z = a2; r.w = a3;
        ((float4*)wvrow)[j >> 2] = r;
    }
}

// ---------------------------------------------------------------------------
// CSR build step 1: histogram of dst.
// ---------------------------------------------------------------------------
__global__ __launch_bounds__(256) void hist_kernel(
    const int* __restrict__ dst, int* __restrict__ cnt) {
    int e = blockIdx.x * 256 + threadIdx.x;
    if (e >= N_EDGES) return;
    atomicAdd(&cnt[dst[e]], 1);
}

// CSR build step 2a: per-block exclusive scan (Hillis-Steele in LDS).
__global__ __launch_bounds__(SCAN_BLK) void scan1_kernel(
    const int* __restrict__ cnt, int* __restrict__ row,
    int* __restrict__ bsum) {
    __shared__ int sh[SCAN_BLK];
    int tid = threadIdx.x;
    int i = blockIdx.x * SCAN_BLK + tid;
    int v = (i < N_NODES) ? cnt[i] : 0;
    sh[tid] = v;
    __syncthreads();
    for (int off = 1; off < SCAN_BLK; off <<= 1) {
        int t = (tid >= off) ? sh[tid - off] : 0;
        __syncthreads();
        sh[tid] += t;
        __syncthreads();
    }
    if (i < N_NODES) row[i] = sh[tid] - v;   // exclusive
    if (tid == SCAN_BLK - 1) bsum[blockIdx.x] = sh[tid];
}

// CSR build step 2b+2c fused: each block redundantly computes the tiny
// 74-element exclusive prefix of block sums, then adds offsets + inits cursor.
__global__ __launch_bounds__(256) void scan23_kernel(
    int* __restrict__ row, const int* __restrict__ bsum,
    int* __restrict__ cursor) {
    __shared__ int pref[N_SCAN_BLKS];
    int tid = threadIdx.x;
    if (tid == 0) {
        int run = 0;
        #pragma unroll 8
        for (int k = 0; k < N_SCAN_BLKS; ++k) { pref[k] = run; run += bsum[k]; }
    }
    __syncthreads();
    int i = blockIdx.x * 256 + tid;
    if (i >= N_NODES) return;
    int r = row[i] + pref[i / SCAN_BLK];
    row[i] = r;
    cursor[i] = r;
}

// CSR build step 3: scatter edge src ids into rows (4 B/edge only).
__global__ __launch_bounds__(256) void build_kernel(
    const int* __restrict__ src, const int* __restrict__ dst,
    int* __restrict__ cursor, int* __restrict__ csr_src) {
    int e = blockIdx.x * 256 + threadIdx.x;
    if (e >= N_EDGES) return;
    int s = src[e];
    int d = dst[e];
    int pos = atomicAdd(&cursor[d], 1);
    csr_src[pos] = s;
}

// ---------------------------------------------------------------------------
// Gather: one wave per dst node.
//   c_j = h_src[s_j] + h_dst[node]   (f64, recomputed — csr_c eliminated)
//   denom = f64 butterfly sum of c_j  (bit-equivalent precision to R3)
//   coef_j = (float)(c_j / denom)     (f32 safe: multiplicative only)
// Fast path (deg <= 64): 2 edges per iteration — lanes 0-31 handle edge
// 2t+0, lanes 32-63 edge 2t+1; each lane loads float2 (2 dims) of the wv
// row. Cross-half reduce at the end; lanes 0-31 store the row as float2.
// ---------------------------------------------------------------------------
__global__ __launch_bounds__(256) void node_gather(
    const int* __restrict__ row, const int* __restrict__ cnt,
    const int* __restrict__ csr_src,
    const double* __restrict__ h_src, const double* __restrict__ h_dst,
    const float* __restrict__ wv, float* __restrict__ out) {
    int gtid = blockIdx.x * 256 + threadIdx.x;
    int node = gtid >> 6;
    int lane = threadIdx.x & 63;
    if (node >= N_NODES) return;

    int start = row[node];
    int deg = cnt[node];
    double hd = h_dst[node];

    if (deg <= 64) {
        // --- fast path ---
        int s0 = 0;
        double c0 = 0.0;
        if (lane < deg) {
            s0 = csr_src[start + lane];
            c0 = h_src[s0] + hd;
        }
        // denom: f64 butterfly over the 64 lanes
        double r = c0;
        #pragma unroll
        for (int off = 32; off > 0; off >>= 1) r += __shfl_xor(r, off, 64);
        double inv = 1.0 / r;
        float cf0 = (lane < deg) ? (float)(c0 * inv) : 0.f;

        int h = lane >> 5;        // which edge of the pair
        int q = lane & 31;        // dim pair index
        int tmax = (deg + 1) >> 1;
        float ax = 0.f, ay = 0.f;
        for (int t = 0; t < tmax; ++t) {
            int idx = 2 * t + h;              // may be == deg when deg odd -> cf 0
            int s = __shfl(s0, idx, 64);
            float cf = __shfl(cf0, idx, 64);
            const float2* rowp = (const float2*)(wv + (size_t)s * DIM);
            float2 w = rowp[q];
            ax += w.x * cf;
            ay += w.y * cf;
        }
        ax += __shfl_xor(ax, 32, 64);
        ay += __shfl_xor(ay, 32, 64);
        if (lane < 32) {
            float2 st; st.x = ax; st.y = ay;
            ((float2*)(out + (size_t)node * DIM))[q] = st;
        }
    } else {
        // --- rare fallback (deg > 64): two-pass chunked, scalar per edge ---
        double denom = 0.0;
        for (int base = 0; base < deg; base += 64) {
            int m = deg - base; if (m > 64) m = 64;
            double c = 0.0;
            if (lane < m) {
                int s = csr_src[start + base + lane];
                c = h_src[s] + hd;
            }
            #pragma unroll
            for (int off = 32; off > 0; off >>= 1) c += __shfl_xor(c, off, 64);
            denom += c;
        }
        double inv = 1.0 / denom;
        float acc = 0.f;
        for (int base = 0; base < deg; base += 64) {
            int m = deg - base; if (m > 64) m = 64;
            int s1 = 0; float cf1 = 0.f;
            if (lane < m) {
                s1 = csr_src[start + base + lane];
                cf1 = (float)((h_src[s1] + hd) * inv);
            }
            for (int j = 0; j < m; ++j) {
                int s = __shfl(s1, j, 64);
                float cf = __shfl(cf1, j, 64);
                acc += wv[(size_t)s * DIM + lane] * cf;
            }
        }
        out[(size_t)node * DIM + lane] = acc;
    }
}

// ---------------------------------------------------------------------------
// Launch
// ---------------------------------------------------------------------------
extern "C" void kernel_launch(void* const* d_in, const int* in_sizes, int n_in,
                              void* d_out, int out_size, void* d_ws, size_t ws_size,
                              hipStream_t stream) {
    const float* d_u = (const float*)d_in[0];
    const float* p_u = (const float*)d_in[1];
    const float* w_q = (const float*)d_in[2];
    const float* w_k = (const float*)d_in[3];
    const float* w_v = (const float*)d_in[4];
    const float* e1  = (const float*)d_in[5];
    const float* e2  = (const float*)d_in[6];
    const int*   src = (const int*)d_in[7];
    const int*   dst = (const int*)d_in[8];
    float* out = (float*)d_out;

    // Workspace: doubles first (8B aligned), then floats, then ints.
    double* a      = (double*)d_ws;
    double* b      = a + DIM;
    double* h_src  = b + DIM;
    double* h_dst  = h_src + N_NODES;
    float*  wv     = (float*)(h_dst + N_NODES);       // N_NODES*DIM floats
    int*    cnt    = (int*)(wv + (size_t)N_NODES * DIM);
    int*    row    = cnt + N_NODES;
    int*    cursor = row + N_NODES;
    int*    bsum   = cursor + N_NODES;                // 128 ints
    int*    csr_src= bsum + 128;                      // N_EDGES ints

    vec_precompute<<<1, 128, 0, stream>>>(w_q, w_k, e1, e2, a, b);

    hipMemsetAsync(cnt, 0, sizeof(int) * N_NODES, stream);

    hist_kernel<<<(N_EDGES + 255) / 256, 256, 0, stream>>>(dst, cnt);

    node_kernel<<<(N_NODES + 255) / 256, 256, 0, stream>>>(
        d_u, p_u, w_v, a, b, h_src, h_dst, wv);

    scan1_kernel<<<N_SCAN_BLKS, SCAN_BLK, 0, stream>>>(cnt, row, bsum);
    scan23_kernel<<<(N_NODES + 255) / 256, 256, 0, stream>>>(row, bsum, cursor);

    build_kernel<<<(N_EDGES + 255) / 256, 256, 0, stream>>>(
        src, dst, cursor, csr_src);

    node_gather<<<(N_NODES * 64 + 255) / 256, 256, 0, stream>>>(
        row, cnt, csr_src, h_src, h_dst, wv, out);
}

// Round 5
// 276.629 us; speedup vs baseline: 2.3920x; 1.2612x over previous
//
#include <hip/hip_runtime.h>

#define N_NODES 75000
#define N_EDGES 1200000
#define DIM 64
#define SCAN_BLK 1024
#define N_SCAN_BLKS ((N_NODES + SCAN_BLK - 1) / SCAN_BLK)   // 74

// ---------------------------------------------------------------------------
// Kernel A (f64): a[d] = sum_j e1[j]*w_k[j][d];  b[d] = sum_j e2[j]*w_q[j][d]
// ---------------------------------------------------------------------------
__global__ void vec_precompute(const float* __restrict__ w_q,
                               const float* __restrict__ w_k,
                               const float* __restrict__ e1,
                               const float* __restrict__ e2,
                               double* __restrict__ a,
                               double* __restrict__ b) {
    int t = threadIdx.x;
    if (t < DIM) {
        double s = 0.0;
        #pragma unroll
        for (int j = 0; j < DIM; ++j) s += (double)e1[j] * (double)w_k[j * DIM + t];
        a[t] = s;
    } else if (t < 2 * DIM) {
        int d = t - DIM;
        double s = 0.0;
        #pragma unroll
        for (int j = 0; j < DIM; ++j) s += (double)e2[j] * (double)w_q[j * DIM + d];
        b[d] = s;
    }
}

// ---------------------------------------------------------------------------
// Kernel B: per-node precompute. h_src/h_dst f64 (precision-critical);
// wv = p_u @ w_v^T in f32, fully unrolled (w_v indices compile-time ->
// scalar s_load broadcasts).
// ---------------------------------------------------------------------------
__global__ __launch_bounds__(256) void node_kernel(
    const float* __restrict__ d_u, const float* __restrict__ p_u,
    const float* __restrict__ w_v,
    const double* __restrict__ a_vec, const double* __restrict__ b_vec,
    double* __restrict__ h_src, double* __restrict__ h_dst,
    float* __restrict__ wv_out) {
    int i = blockIdx.x * 256 + threadIdx.x;
    if (i >= N_NODES) return;

    float p[DIM];
    const float4* prow = (const float4*)(p_u + (size_t)i * DIM);
    #pragma unroll
    for (int k = 0; k < DIM / 4; ++k) {
        float4 v = prow[k];
        p[4 * k + 0] = v.x; p[4 * k + 1] = v.y;
        p[4 * k + 2] = v.z; p[4 * k + 3] = v.w;
    }

    double hs = 0.0;
    #pragma unroll
    for (int d = 0; d < DIM; ++d) hs += (double)p[d] * a_vec[d];
    h_src[i] = hs;

    double hd = 0.0;
    const float4* drow = (const float4*)(d_u + (size_t)i * DIM);
    #pragma unroll
    for (int k = 0; k < DIM / 4; ++k) {
        float4 v = drow[k];
        hd += (double)v.x * b_vec[4 * k + 0] + (double)v.y * b_vec[4 * k + 1] +
              (double)v.z * b_vec[4 * k + 2] + (double)v.w * b_vec[4 * k + 3];
    }
    h_dst[i] = hd;

    float* wvrow = wv_out + (size_t)i * DIM;
    #pragma unroll
    for (int j = 0; j < DIM; j += 4) {
        float a0 = 0.f, a1 = 0.f, a2 = 0.f, a3 = 0.f;
        #pragma unroll
        for (int d = 0; d < DIM; ++d) {
            float pd = p[d];
            a0 += w_v[(j + 0) * DIM + d] * pd;
            a1 += w_v[(j + 1) * DIM + d] * pd;
            a2 += w_v[(j + 2) * DIM + d] * pd;
            a3 += w_v[(j + 3) * DIM + d] * pd;
        }
        float4 r; r.x = a0; r.y = a1; r.z = a2; r.w = a3;
        ((float4*)wvrow)[j >> 2] = r;
    }
}

// ---------------------------------------------------------------------------
// CSR step 1: histogram of dst + per-edge rank (coalesced 4B write).
// Moves the contended atomic out of the scatter kernel.
// ---------------------------------------------------------------------------
__global__ __launch_bounds__(256) void hist_kernel(
    const int* __restrict__ dst, int* __restrict__ cnt,
    int* __restrict__ rank) {
    int e = blockIdx.x * 256 + threadIdx.x;
    if (e >= N_EDGES) return;
    rank[e] = atomicAdd(&cnt[dst[e]], 1);
}

// CSR step 2a: per-block exclusive scan (Hillis-Steele in LDS).
__global__ __launch_bounds__(SCAN_BLK) void scan1_kernel(
    const int* __restrict__ cnt, int* __restrict__ row,
    int* __restrict__ bsum) {
    __shared__ int sh[SCAN_BLK];
    int tid = threadIdx.x;
    int i = blockIdx.x * SCAN_BLK + tid;
    int v = (i < N_NODES) ? cnt[i] : 0;
    sh[tid] = v;
    __syncthreads();
    for (int off = 1; off < SCAN_BLK; off <<= 1) {
        int t = (tid >= off) ? sh[tid - off] : 0;
        __syncthreads();
        sh[tid] += t;
        __syncthreads();
    }
    if (i < N_NODES) row[i] = sh[tid] - v;   // exclusive
    if (tid == SCAN_BLK - 1) bsum[blockIdx.x] = sh[tid];
}

// CSR step 2b: add block-sum prefix (redundant tiny scan per block).
__global__ __launch_bounds__(256) void scan23_kernel(
    int* __restrict__ row, const int* __restrict__ bsum) {
    __shared__ int pref[N_SCAN_BLKS];
    int tid = threadIdx.x;
    if (tid == 0) {
        int run = 0;
        #pragma unroll 8
        for (int k = 0; k < N_SCAN_BLKS; ++k) { pref[k] = run; run += bsum[k]; }
    }
    __syncthreads();
    int i = blockIdx.x * 256 + tid;
    if (i >= N_NODES) return;
    row[i] += pref[i / SCAN_BLK];
}

// CSR step 3: atomic-free scatter of src ids. pos is deterministic:
// row[d] (L2-resident gather) + rank[e] (coalesced).
__global__ __launch_bounds__(256) void build_kernel(
    const int* __restrict__ src, const int* __restrict__ dst,
    const int* __restrict__ row, const int* __restrict__ rank,
    int* __restrict__ csr_src) {
    int e = blockIdx.x * 256 + threadIdx.x;
    if (e >= N_EDGES) return;
    int pos = row[dst[e]] + rank[e];
    csr_src[pos] = src[e];
}

// ---------------------------------------------------------------------------
// Gather: one wave per dst node.
//   c_j = h_src[s_j] + h_dst[node]   (f64)
//   denom = f64 butterfly sum (byte-identical to R3/R4 — precision path)
//   coef_j = (float)(c_j / denom)
// Fast path (deg <= 64): 4 edges/iter — 4 lane-groups of 16; each lane
// loads one float4 (16B) of its edge's wv row. Cross-group reduce via
// shfl_xor(16/32); lanes 0-15 store the 256B row as float4.
// ---------------------------------------------------------------------------
__global__ __launch_bounds__(256) void node_gather(
    const int* __restrict__ row, const int* __restrict__ cnt,
    const int* __restrict__ csr_src,
    const double* __restrict__ h_src, const double* __restrict__ h_dst,
    const float* __restrict__ wv, float* __restrict__ out) {
    int gtid = blockIdx.x * 256 + threadIdx.x;
    int node = gtid >> 6;
    int lane = threadIdx.x & 63;
    if (node >= N_NODES) return;

    int start = row[node];
    int deg = cnt[node];
    double hd = h_dst[node];

    if (deg <= 64) {
        // --- fast path ---
        int s0 = 0;
        double c0 = 0.0;
        if (lane < deg) {
            s0 = csr_src[start + lane];
            c0 = h_src[s0] + hd;
        }
        // denom: f64 butterfly (identical order to previous rounds)
        double r = c0;
        #pragma unroll
        for (int off = 32; off > 0; off >>= 1) r += __shfl_xor(r, off, 64);
        double inv = 1.0 / r;
        float cf0 = (lane < deg) ? (float)(c0 * inv) : 0.f;

        int g = lane >> 4;        // edge-in-quad (0..3)
        int q = lane & 15;        // float4 index within row
        int tmax = (deg + 3) >> 2;
        float ax = 0.f, ay = 0.f, az = 0.f, aw = 0.f;
        for (int t = 0; t < tmax; ++t) {
            int idx = 4 * t + g;              // idx >= deg -> cf 0 (s0 def 0)
            int s = __shfl(s0, idx, 64);
            float cf = __shfl(cf0, idx, 64);
            const float4* rowp = (const float4*)(wv + (size_t)s * DIM);
            float4 w = rowp[q];
            ax += w.x * cf;
            ay += w.y * cf;
            az += w.z * cf;
            aw += w.w * cf;
        }
        ax += __shfl_xor(ax, 16, 64);
        ay += __shfl_xor(ay, 16, 64);
        az += __shfl_xor(az, 16, 64);
        aw += __shfl_xor(aw, 16, 64);
        ax += __shfl_xor(ax, 32, 64);
        ay += __shfl_xor(ay, 32, 64);
        az += __shfl_xor(az, 32, 64);
        aw += __shfl_xor(aw, 32, 64);
        if (lane < 16) {
            float4 st; st.x = ax; st.y = ay; st.z = az; st.w = aw;
            ((float4*)(out + (size_t)node * DIM))[q] = st;
        }
    } else {
        // --- rare fallback (deg > 64): two-pass chunked ---
        double denom = 0.0;
        for (int base = 0; base < deg; base += 64) {
            int m = deg - base; if (m > 64) m = 64;
            double c = 0.0;
            if (lane < m) {
                int s = csr_src[start + base + lane];
                c = h_src[s] + hd;
            }
            #pragma unroll
            for (int off = 32; off > 0; off >>= 1) c += __shfl_xor(c, off, 64);
            denom += c;
        }
        double inv = 1.0 / denom;
        float acc = 0.f;
        for (int base = 0; base < deg; base += 64) {
            int m = deg - base; if (m > 64) m = 64;
            int s1 = 0; float cf1 = 0.f;
            if (lane < m) {
                s1 = csr_src[start + base + lane];
                cf1 = (float)((h_src[s1] + hd) * inv);
            }
            for (int j = 0; j < m; ++j) {
                int s = __shfl(s1, j, 64);
                float cf = __shfl(cf1, j, 64);
                acc += wv[(size_t)s * DIM + lane] * cf;
            }
        }
        out[(size_t)node * DIM + lane] = acc;
    }
}

// ---------------------------------------------------------------------------
// Launch
// ---------------------------------------------------------------------------
extern "C" void kernel_launch(void* const* d_in, const int* in_sizes, int n_in,
                              void* d_out, int out_size, void* d_ws, size_t ws_size,
                              hipStream_t stream) {
    const float* d_u = (const float*)d_in[0];
    const float* p_u = (const float*)d_in[1];
    const float* w_q = (const float*)d_in[2];
    const float* w_k = (const float*)d_in[3];
    const float* w_v = (const float*)d_in[4];
    const float* e1  = (const float*)d_in[5];
    const float* e2  = (const float*)d_in[6];
    const int*   src = (const int*)d_in[7];
    const int*   dst = (const int*)d_in[8];
    float* out = (float*)d_out;

    // Workspace: doubles first (8B aligned), then floats, then ints.
    double* a      = (double*)d_ws;
    double* b      = a + DIM;
    double* h_src  = b + DIM;
    double* h_dst  = h_src + N_NODES;
    float*  wv     = (float*)(h_dst + N_NODES);       // N_NODES*DIM floats
    int*    cnt    = (int*)(wv + (size_t)N_NODES * DIM);
    int*    row    = cnt + N_NODES;
    int*    bsum   = row + N_NODES;                   // 128 ints
    int*    rank   = bsum + 128;                      // N_EDGES ints
    int*    csr_src= rank + N_EDGES;                  // N_EDGES ints

    vec_precompute<<<1, 128, 0, stream>>>(w_q, w_k, e1, e2, a, b);

    hipMemsetAsync(cnt, 0, sizeof(int) * N_NODES, stream);

    hist_kernel<<<(N_EDGES + 255) / 256, 256, 0, stream>>>(dst, cnt, rank);

    node_kernel<<<(N_NODES + 255) / 256, 256, 0, stream>>>(
        d_u, p_u, w_v, a, b, h_src, h_dst, wv);

    scan1_kernel<<<N_SCAN_BLKS, SCAN_BLK, 0, stream>>>(cnt, row, bsum);
    scan23_kernel<<<(N_NODES + 255) / 256, 256, 0, stream>>>(row, bsum);

    build_kernel<<<(N_EDGES + 255) / 256, 256, 0, stream>>>(
        src, dst, row, rank, csr_src);

    node_gather<<<(N_NODES * 64 + 255) / 256, 256, 0, stream>>>(
        row, cnt, csr_src, h_src, h_dst, wv, out);
}